// Round 5
// baseline (93.883 us; speedup 1.0000x reference)
//
#include <hip/hip_runtime.h>

// RationalRMSNorm: x [B,S,H=4096] fp32, weight [H] fp32 -> out fp32
// One WAVE per row (64 lanes x 4 float4 = 4096 floats): no LDS, no barrier.
// Butterfly __shfl_xor reduce gives every lane the row total; each lane
// redundantly runs the scalar Newton chain (VALU is nearly idle anyway).
// Nontemporal loads/stores on the streamed x/out; weight stays cacheable.

typedef float f32x4 __attribute__((ext_vector_type(4)));

constexpr int H = 4096;
constexpr int THREADS = 256;
constexpr int WAVES_PER_BLOCK = THREADS / 64;       // 4 rows per block
constexpr int VECS_PER_LANE = H / (64 * 4);         // 4

__global__ __launch_bounds__(THREADS)
void rational_rmsnorm_kernel(const float* __restrict__ x,
                             const float* __restrict__ w,
                             float* __restrict__ out) {
    const int wave = threadIdx.x >> 6;
    const int lane = threadIdx.x & 63;
    const long long row = (long long)blockIdx.x * WAVES_PER_BLOCK + wave;

    const f32x4* xr = reinterpret_cast<const f32x4*>(x + row * (long long)H);
    f32x4* outr     = reinterpret_cast<f32x4*>(out + row * (long long)H);
    const f32x4* wv4 = reinterpret_cast<const f32x4*>(w);

    f32x4 v[VECS_PER_LANE];
    f32x4 wv[VECS_PER_LANE];
#pragma unroll
    for (int i = 0; i < VECS_PER_LANE; ++i)
        v[i] = __builtin_nontemporal_load(&xr[i * 64 + lane]);
#pragma unroll
    for (int i = 0; i < VECS_PER_LANE; ++i)
        wv[i] = wv4[i * 64 + lane];                 // L2-resident, in flight during reduce

    float sumsq = 0.0f;
#pragma unroll
    for (int i = 0; i < VECS_PER_LANE; ++i)
        sumsq += v[i].x * v[i].x + v[i].y * v[i].y
               + v[i].z * v[i].z + v[i].w * v[i].w;

    // 64-lane butterfly: every lane ends with the full row sum.
#pragma unroll
    for (int off = 32; off > 0; off >>= 1)
        sumsq += __shfl_xor(sumsq, off, 64);

    // Scalar chain, replicated per lane (op-for-op match to the reference).
    float variance = sumsq * (1.0f / (float)H);
    variance = fmaxf(variance, 1e-8f);
    float xs = variance + 1e-6f;
    xs = fmaxf(xs, 1e-8f);
    float log_x = log10f(xs + 1.0f);
    float scale_exp = floorf(log_x / 2.0f) * 2.0f;
    float scale = powf(10.0f, scale_exp);
    float x_norm = xs / scale;
    float y = 0.1f;
    float half_x = 0.5f * x_norm;
#pragma unroll
    for (int i = 0; i < 10; ++i)
        y = y * (1.5f - half_x * (y * y));
    float inv_sqrt_scale = powf(10.0f, -scale_exp / 2.0f);
    const float inv = y * inv_sqrt_scale;

#pragma unroll
    for (int i = 0; i < VECS_PER_LANE; ++i) {
        f32x4 o = v[i] * inv * wv[i];
        __builtin_nontemporal_store(o, &outr[i * 64 + lane]);
    }
}

extern "C" void kernel_launch(void* const* d_in, const int* in_sizes, int n_in,
                              void* d_out, int out_size, void* d_ws, size_t ws_size,
                              hipStream_t stream) {
    const float* x = (const float*)d_in[0];
    const float* w = (const float*)d_in[1];
    float* out = (float*)d_out;
    const int nrows = in_sizes[0] / H;              // B*S = 16384
    rational_rmsnorm_kernel<<<nrows / WAVES_PER_BLOCK, THREADS, 0, stream>>>(x, w, out);
}

// Round 6
// 92.578 us; speedup vs baseline: 1.0141x; 1.0141x over previous
//
#include <hip/hip_runtime.h>

// RationalRMSNorm: x [B,S,H=4096] fp32, weight [H] fp32 -> out fp32
// One WAVE handles TWO rows (independent streams -> ILP hides the per-row
// load->reduce->store dependency bubble). 64 lanes x 4 float4 = one row.
// No LDS, no barriers. Newton-10 chain replaced by rsqrtf (mathematically
// converged-identical, rel err <1e-7 vs 0.11 threshold).
// Nontemporal loads/stores on streamed x/out; weight loaded once per wave.

typedef float f32x4 __attribute__((ext_vector_type(4)));

constexpr int H = 4096;
constexpr int THREADS = 256;
constexpr int WAVES_PER_BLOCK = THREADS / 64;   // 4
constexpr int ROWS_PER_WAVE = 2;
constexpr int VECS_PER_LANE = H / (64 * 4);     // 4

__global__ __launch_bounds__(THREADS)
void rational_rmsnorm_kernel(const float* __restrict__ x,
                             const float* __restrict__ w,
                             float* __restrict__ out) {
    const int wave = threadIdx.x >> 6;
    const int lane = threadIdx.x & 63;
    const long long wid = (long long)blockIdx.x * WAVES_PER_BLOCK + wave;
    const long long row0 = wid * ROWS_PER_WAVE;

    const f32x4* xr0 = reinterpret_cast<const f32x4*>(x + row0 * (long long)H);
    const f32x4* xr1 = reinterpret_cast<const f32x4*>(x + (row0 + 1) * (long long)H);
    f32x4* or0       = reinterpret_cast<f32x4*>(out + row0 * (long long)H);
    f32x4* or1       = reinterpret_cast<f32x4*>(out + (row0 + 1) * (long long)H);
    const f32x4* wv4 = reinterpret_cast<const f32x4*>(w);

    f32x4 v0[VECS_PER_LANE], v1[VECS_PER_LANE], wv[VECS_PER_LANE];
#pragma unroll
    for (int i = 0; i < VECS_PER_LANE; ++i) {
        v0[i] = __builtin_nontemporal_load(&xr0[i * 64 + lane]);
        v1[i] = __builtin_nontemporal_load(&xr1[i * 64 + lane]);
    }
#pragma unroll
    for (int i = 0; i < VECS_PER_LANE; ++i)
        wv[i] = wv4[i * 64 + lane];                 // L2-resident

    float s0 = 0.0f, s1 = 0.0f;
#pragma unroll
    for (int i = 0; i < VECS_PER_LANE; ++i) {
        s0 += v0[i].x * v0[i].x + v0[i].y * v0[i].y
            + v0[i].z * v0[i].z + v0[i].w * v0[i].w;
        s1 += v1[i].x * v1[i].x + v1[i].y * v1[i].y
            + v1[i].z * v1[i].z + v1[i].w * v1[i].w;
    }

    // Two interleaved 64-lane butterflies (independent -> latency shared).
#pragma unroll
    for (int off = 32; off > 0; off >>= 1) {
        s0 += __shfl_xor(s0, off, 64);
        s1 += __shfl_xor(s1, off, 64);
    }

    // variance clip + eps, then rsqrt (== converged Newton-10 of reference).
    const float inv0 = rsqrtf(fmaxf(s0 * (1.0f / (float)H), 1e-8f) + 1e-6f);
    const float inv1 = rsqrtf(fmaxf(s1 * (1.0f / (float)H), 1e-8f) + 1e-6f);

#pragma unroll
    for (int i = 0; i < VECS_PER_LANE; ++i) {
        __builtin_nontemporal_store(v0[i] * inv0 * wv[i], &or0[i * 64 + lane]);
        __builtin_nontemporal_store(v1[i] * inv1 * wv[i], &or1[i * 64 + lane]);
    }
}

extern "C" void kernel_launch(void* const* d_in, const int* in_sizes, int n_in,
                              void* d_out, int out_size, void* d_ws, size_t ws_size,
                              hipStream_t stream) {
    const float* x = (const float*)d_in[0];
    const float* w = (const float*)d_in[1];
    float* out = (float*)d_out;
    const int nrows = in_sizes[0] / H;              // B*S = 16384
    const int blocks = nrows / (WAVES_PER_BLOCK * ROWS_PER_WAVE); // 2048
    rational_rmsnorm_kernel<<<blocks, THREADS, 0, stream>>>(x, w, out);
}

// Round 7
// 86.420 us; speedup vs baseline: 1.0864x; 1.0713x over previous
//
#include <hip/hip_runtime.h>

// RationalRMSNorm: x [B,S,H=4096] fp32, weight [H] fp32 -> out fp32
// One WAVE handles TWO rows; 64 lanes x 4 float4 = one row. No LDS/barriers.
// A/B isolation of R4's bundled change: loads are now NORMAL (cached) —
// nt-loads may take a lower-efficiency TCC path; the copy ubench ceiling
// (6.29 TB/s) was measured with cached accesses. Stores stay nontemporal
// (write-allocate avoidance is the real win).

typedef float f32x4 __attribute__((ext_vector_type(4)));

constexpr int H = 4096;
constexpr int THREADS = 256;
constexpr int WAVES_PER_BLOCK = THREADS / 64;   // 4
constexpr int ROWS_PER_WAVE = 2;
constexpr int VECS_PER_LANE = H / (64 * 4);     // 4

__global__ __launch_bounds__(THREADS)
void rational_rmsnorm_kernel(const float* __restrict__ x,
                             const float* __restrict__ w,
                             float* __restrict__ out) {
    const int wave = threadIdx.x >> 6;
    const int lane = threadIdx.x & 63;
    const long long wid = (long long)blockIdx.x * WAVES_PER_BLOCK + wave;
    const long long row0 = wid * ROWS_PER_WAVE;

    const f32x4* xr0 = reinterpret_cast<const f32x4*>(x + row0 * (long long)H);
    const f32x4* xr1 = reinterpret_cast<const f32x4*>(x + (row0 + 1) * (long long)H);
    f32x4* or0       = reinterpret_cast<f32x4*>(out + row0 * (long long)H);
    f32x4* or1       = reinterpret_cast<f32x4*>(out + (row0 + 1) * (long long)H);
    const f32x4* wv4 = reinterpret_cast<const f32x4*>(w);

    f32x4 v0[VECS_PER_LANE], v1[VECS_PER_LANE], wv[VECS_PER_LANE];
#pragma unroll
    for (int i = 0; i < VECS_PER_LANE; ++i) {
        v0[i] = xr0[i * 64 + lane];                 // cached loads
        v1[i] = xr1[i * 64 + lane];
    }
#pragma unroll
    for (int i = 0; i < VECS_PER_LANE; ++i)
        wv[i] = wv4[i * 64 + lane];                 // L2-resident

    float s0 = 0.0f, s1 = 0.0f;
#pragma unroll
    for (int i = 0; i < VECS_PER_LANE; ++i) {
        s0 += v0[i].x * v0[i].x + v0[i].y * v0[i].y
            + v0[i].z * v0[i].z + v0[i].w * v0[i].w;
        s1 += v1[i].x * v1[i].x + v1[i].y * v1[i].y
            + v1[i].z * v1[i].z + v1[i].w * v1[i].w;
    }

#pragma unroll
    for (int off = 32; off > 0; off >>= 1) {
        s0 += __shfl_xor(s0, off, 64);
        s1 += __shfl_xor(s1, off, 64);
    }

    const float inv0 = rsqrtf(fmaxf(s0 * (1.0f / (float)H), 1e-8f) + 1e-6f);
    const float inv1 = rsqrtf(fmaxf(s1 * (1.0f / (float)H), 1e-8f) + 1e-6f);

#pragma unroll
    for (int i = 0; i < VECS_PER_LANE; ++i) {
        __builtin_nontemporal_store(v0[i] * inv0 * wv[i], &or0[i * 64 + lane]);
        __builtin_nontemporal_store(v1[i] * inv1 * wv[i], &or1[i * 64 + lane]);
    }
}

extern "C" void kernel_launch(void* const* d_in, const int* in_sizes, int n_in,
                              void* d_out, int out_size, void* d_ws, size_t ws_size,
                              hipStream_t stream) {
    const float* x = (const float*)d_in[0];
    const float* w = (const float*)d_in[1];
    float* out = (float*)d_out;
    const int nrows = in_sizes[0] / H;              // B*S = 16384
    const int blocks = nrows / (WAVES_PER_BLOCK * ROWS_PER_WAVE); // 2048
    rational_rmsnorm_kernel<<<blocks, THREADS, 0, stream>>>(x, w, out);
}